// Round 11
// baseline (1994.669 us; speedup 1.0000x reference)
//
#include <hip/hip_runtime.h>
#include <hip/hip_bf16.h>
#include <hip/hip_cooperative_groups.h>

typedef __attribute__((ext_vector_type(8))) short bf16x8;
typedef __attribute__((ext_vector_type(4))) float f32x4;
typedef __attribute__((ext_vector_type(4))) unsigned int u32x4;

#define D_ 1024
#define T_ 1024
#define B_ 8
#define M_ (T_ * B_)

__device__ __forceinline__ float ldv(const float* p) { return *p; }
__device__ __forceinline__ float ldv(const __hip_bfloat16* p) { return __bfloat162float(*p); }
__device__ __forceinline__ void stv(float* p, float v) { *p = v; }
__device__ __forceinline__ void stv(__hip_bfloat16* p, float v) { *p = __float2bfloat16(v); }

// --- MALL-coherent accessors (round-4/7-proven): sc0 sc1 bypasses L1+L2 ----
__device__ __forceinline__ u32x4 ld_chunk(const unsigned* p) {
  u32x4 v;
  asm volatile("global_load_dwordx4 %0, %1, off sc0 sc1" : "=v"(v) : "v"(p) : "memory");
  return v;
}
__device__ __forceinline__ void st_word(unsigned* p, unsigned v) {
  asm volatile("global_store_dword %0, %1, off sc0 sc1" :: "v"(p), "v"(v) : "memory");
}
__device__ __forceinline__ void wait_vm0() {
  asm volatile("s_waitcnt vmcnt(0)" ::: "memory");
}
// LDS-only workgroup barrier (no vmcnt drain).
__device__ __forceinline__ void bar_lds() {
  asm volatile("s_waitcnt lgkmcnt(0)\n\ts_barrier" ::: "memory");
  __builtin_amdgcn_sched_barrier(0);
}
// native 2^x / 1/x
__device__ __forceinline__ float exp2_fast(float x) {
  float r;
  asm("v_exp_f32 %0, %1" : "=v"(r) : "v"(x));
  return r;
}
__device__ __forceinline__ float rcp_fast(float x) {
  float r;
  asm("v_rcp_f32 %0, %1" : "=v"(r) : "v"(x));
  return r;
}

// ---------------------------------------------------------------------------
// f32 -> bf16 bulk convert (8 elems/thread, vectorized)
// ---------------------------------------------------------------------------
__global__ __launch_bounds__(256) void conv_bf16(const float* __restrict__ in,
                                                 __hip_bfloat16* __restrict__ out,
                                                 int n8)
{
  int i = blockIdx.x * blockDim.x + threadIdx.x;
  const int stride = gridDim.x * blockDim.x;
  for (; i < n8; i += stride) {
    const f32x4* p = reinterpret_cast<const f32x4*>(in + (size_t)i * 8);
    f32x4 a = p[0], b = p[1];
    union { bf16x8 v; __hip_bfloat16 e[8]; } u;
#pragma unroll
    for (int j = 0; j < 4; ++j) {
      u.e[j] = __float2bfloat16(a[j]);
      u.e[j + 4] = __float2bfloat16(b[j]);
    }
    *reinterpret_cast<bf16x8*>(out + (size_t)i * 8) = u.v;
  }
}

// ---------------------------------------------------------------------------
// Phase 1: alpha_all = sigmoid(xb @ Wab^T + b_alpha), wx_all = xb @ Wxb^T + b
// (unchanged — verified correct)
// ---------------------------------------------------------------------------
template <typename ST>
__global__ __launch_bounds__(256) void gemm_front(
    const __hip_bfloat16* __restrict__ xb,
    const __hip_bfloat16* __restrict__ Wab,
    const float* __restrict__ ba,
    const __hip_bfloat16* __restrict__ Wxb,
    const float* __restrict__ bbias,
    ST* __restrict__ alpha_out,
    ST* __restrict__ wx_out)
{
  const int tid = threadIdx.x;
  const int lane = tid & 63;
  const int w = tid >> 6;
  const int r = lane & 15;
  const int g = lane >> 4;
  const bool isA = blockIdx.y < 8;
  const int m0 = blockIdx.x * 128 + (w >> 1) * 64;
  const int n0 = (blockIdx.y & 7) * 128 + (w & 1) * 64;
  const __hip_bfloat16* __restrict__ W = isA ? Wab : Wxb;
  ST* __restrict__ outp = isA ? alpha_out : wx_out;

  f32x4 acc[4][4] = {};

  const __hip_bfloat16* aBase = xb + (size_t)(m0 + r) * D_ + g * 8;
  const __hip_bfloat16* bBase = W + (size_t)(n0 + r) * D_ + g * 8;

  for (int k = 0; k < D_; k += 32) {
    bf16x8 a[4], b[4];
#pragma unroll
    for (int mt = 0; mt < 4; ++mt)
      a[mt] = *reinterpret_cast<const bf16x8*>(aBase + (size_t)mt * 16 * D_ + k);
#pragma unroll
    for (int nt = 0; nt < 4; ++nt)
      b[nt] = *reinterpret_cast<const bf16x8*>(bBase + (size_t)nt * 16 * D_ + k);
#pragma unroll
    for (int mt = 0; mt < 4; ++mt)
#pragma unroll
      for (int nt = 0; nt < 4; ++nt)
        acc[mt][nt] = __builtin_amdgcn_mfma_f32_16x16x32_bf16(a[mt], b[nt], acc[mt][nt], 0, 0, 0);
  }

#pragma unroll
  for (int nt = 0; nt < 4; ++nt) {
    const int col = n0 + nt * 16 + r;
    const float bias = isA ? ba[col] : bbias[col];
#pragma unroll
    for (int mt = 0; mt < 4; ++mt) {
      const int row = m0 + mt * 16 + g * 4;
#pragma unroll
      for (int i = 0; i < 4; ++i) {
        float v = acc[mt][nt][i] + bias;
        if (isA) v = 1.0f / (1.0f + expf(-v));
        stv(outp + (size_t)(row + i) * D_ + col, v);
      }
    }
  }
}

// ---------------------------------------------------------------------------
// Phase 2: batch-island scan, word-atomic tag-in-payload, MALL scope.
// r11: SINGLE barrier per step.
//  - Own slice consumed via ring like foreign slices -> h_lds is wave-private
//    (only the staging wave reads its quarter) -> no barrier needed for h_lds.
//  - C_lds double-buffered [2][64][4] (parity t&1) + transposed so finish
//    reads one ds_read_b128 -> WAR edge needs no second barrier.
//  - bar_lds remains only between C_lds writes and the wave-0 finish reduce.
//  - Waves 1-3 run ahead into poll(t+1) while wave 0 finishes/publishes.
//  - Poll: per-lane exit (no ballot; satisfied lanes stop reloading).
//  - MFMA: 8 acc chains (depth 4) for shorter dependency latency.
// Ring lap-safety through bar#1 alone: producer overwrite(tag t+2, parity
// (t+1)&1) <- own-WG stage(t) observed tags t+1 from ALL slices <- each
// slice published t+1 after ITS bar#1(t-1) <- its waves' stage(t-1) = every
// reader's completed read of tag-t words at parity (t+1)&1.  QED.
// ---------------------------------------------------------------------------
template <typename ST>
__global__ __launch_bounds__(256) void scan_rec(
    const float* __restrict__ h0,
    const float* __restrict__ Wh,
    const ST* __restrict__ alpha_all,
    const ST* __restrict__ wx_all,
    unsigned* __restrict__ ring,     // [2][B][1024] u32 words, memset 0
    float* __restrict__ out_outs,    // [T][B][D] f32
    float* __restrict__ out_h)       // [T+1][B][D] f32
{
  __shared__ __align__(16) unsigned short W_lds[64 * 1024];  // 128 KB, swizzled
  __shared__ __align__(16) unsigned short h_lds[1024];       // wave-private quarters
  __shared__ __align__(16) float C_lds[2][64][4];            // [parity][col][wave]

  const int tid = threadIdx.x;
  const int lane = tid & 63;
  const int w = tid >> 6;
  const int r = lane & 15;
  const int g = lane >> 4;
  const int bb = blockIdx.x & 7;   // batch
  const int s = blockIdx.x >> 3;   // col slice
  const int e0 = s * 64;

  // ---- Stage W_h rows e0..e0+63 into LDS as bf16, XOR-swizzled ----
  for (int idx = tid; idx < 64 * 128; idx += 256) {
    const int row = idx >> 7;        // 0..63
    const int k8 = (idx & 127) * 8;  // k chunk start
    const f32x4* p = reinterpret_cast<const f32x4*>(Wh + (size_t)(e0 + row) * D_ + k8);
    f32x4 a = p[0], bv = p[1];
    union { bf16x8 v; __hip_bfloat16 e[8]; } u;
#pragma unroll
    for (int j = 0; j < 4; ++j) {
      u.e[j] = __float2bfloat16(a[j]);
      u.e[j + 4] = __float2bfloat16(bv[j]);
    }
    const unsigned byteoff = ((unsigned)row * 2048u + (unsigned)k8 * 2u) ^ (((unsigned)row & 7u) << 4);
    *reinterpret_cast<bf16x8*>(reinterpret_cast<char*>(W_lds) + byteoff) = u.v;
  }

  // ---- Init: finish threads (wave 0, col e0+tid); publish slot0 tag=1 ----
  const int e = e0 + (tid & 63);  // finish col (valid for tid<64)
  float h_f = 0.0f, wx_c = 0.0f, al_c = 0.0f;
  if (tid < 64) {
    h_f = h0[bb * D_ + e];
    out_h[(size_t)bb * D_ + e] = h_f;
    const unsigned short hb = ((__hip_bfloat16_raw)__float2bfloat16(h_f)).x;
    st_word(ring + (size_t)bb * 1024 + e, (unsigned)hb | (1u << 16));
    wx_c = ldv(wx_all + (size_t)bb * D_ + e);
    al_c = ldv(alpha_all + (size_t)bb * D_ + e);
  }
  __syncthreads();  // W_lds staged

  for (int t = 0; t < T_; ++t) {
    // ---- stage h[t] quarter (lanes 0..31, 8 words each, OWN slice incl.) ----
    const unsigned want = (unsigned)(t + 1);
    const int kk = w * 256 + lane * 8;
    if (lane < 32) {
      const unsigned* cp = ring + ((size_t)(t & 1) * B_ + bb) * 1024 + kk;
      u32x4 A, Bv;
      int bail = 0;
      for (;;) {
        A = ld_chunk(cp);
        Bv = ld_chunk(cp + 4);
        wait_vm0();
        const bool ok = (A[0] >> 16) == want && (A[1] >> 16) == want &&
                        (A[2] >> 16) == want && (A[3] >> 16) == want &&
                        (Bv[0] >> 16) == want && (Bv[1] >> 16) == want &&
                        (Bv[2] >> 16) == want && (Bv[3] >> 16) == want;
        if (ok || ++bail > (1 << 20)) break;  // per-lane exit
      }
      u32x4 hw;
      hw[0] = (A[0] & 0xffffu) | (A[1] << 16);
      hw[1] = (A[2] & 0xffffu) | (A[3] << 16);
      hw[2] = (Bv[0] & 0xffffu) | (Bv[1] << 16);
      hw[3] = (Bv[2] & 0xffffu) | (Bv[3] << 16);
      *reinterpret_cast<u32x4*>(&h_lds[kk]) = hw;
    }
    asm volatile("s_waitcnt lgkmcnt(0)" ::: "memory");
    __builtin_amdgcn_sched_barrier(0);

    // ---- MFMA: y_partial[64] over this wave's K quarter (8 acc chains) ----
    f32x4 acc[4][2] = {};
#pragma unroll
    for (int kt = 0; kt < 8; ++kt) {
      const int k = w * 256 + kt * 32 + g * 8;
      bf16x8 afrag = {};
      if (r == 0)
        afrag = *reinterpret_cast<const bf16x8*>(&h_lds[k]);
#pragma unroll
      for (int nt = 0; nt < 4; ++nt) {
        const unsigned row = (unsigned)(nt * 16 + r);
        const unsigned byteoff = (row * 2048u + (unsigned)k * 2u) ^ ((row & 7u) << 4);
        bf16x8 bfrag = *reinterpret_cast<const bf16x8*>(
            reinterpret_cast<const char*>(W_lds) + byteoff);
        acc[nt][kt & 1] = __builtin_amdgcn_mfma_f32_16x16x32_bf16(
            afrag, bfrag, acc[nt][kt & 1], 0, 0, 0);
      }
    }
    if (g == 0) {
#pragma unroll
      for (int nt = 0; nt < 4; ++nt)
        C_lds[t & 1][nt * 16 + r][w] = acc[nt][0][0] + acc[nt][1][0];
    }
    bar_lds();  // C_lds handoff — the ONLY per-step barrier

    // ---- finish (wave 0): recurrence; tagged publish FIRST, outputs after ----
    if (tid < 64) {
      const f32x4 c4 = *reinterpret_cast<const f32x4*>(&C_lds[t & 1][tid][0]);
      const float y = c4[0] + c4[1] + c4[2] + c4[3];
      // tanh(x) = 1 - 2/(2^(2x*log2e)+1)
      const float xs = (y + wx_c) * 2.8853900817779268f;
      const float tv = fmaf(-2.0f, rcp_fast(exp2_fast(xs) + 1.0f), 1.0f);
      h_f = fmaf(al_c, h_f - tv, tv);  // alpha*h + (1-alpha)*v
      const unsigned short hb = ((__hip_bfloat16_raw)__float2bfloat16(h_f)).x;
      st_word(ring + ((size_t)((t + 1) & 1) * B_ + bb) * 1024 + e,
              (unsigned)hb | ((unsigned)(t + 2) << 16));
      // off-chain work after the publish:
      const float sg = rcp_fast(1.0f + exp2_fast(h_f * -1.4426950408889634f));
      const float o = h_f * h_f * sg;  // h * silu(h)
      out_h[(size_t)(t + 1) * (B_ * D_) + (size_t)bb * D_ + e] = h_f;
      out_outs[(size_t)t * (B_ * D_) + (size_t)bb * D_ + e] = o;
      if (t + 1 < T_) {
        wx_c = ldv(wx_all + (size_t)((t + 1) * B_ + bb) * D_ + e);
        al_c = ldv(alpha_all + (size_t)((t + 1) * B_ + bb) * D_ + e);
      }
    }
    // no second barrier: h_lds is wave-private; C_lds parity flips.
  }
}

// ---------------------------------------------------------------------------
template <typename ST>
static void launch_all(const float* x, const float* h0, const float* Wa,
                       const float* ba, const float* Wh, const float* Wx,
                       const float* bb, __hip_bfloat16* xb, __hip_bfloat16* Wab,
                       __hip_bfloat16* Wxb, ST* alpha_buf, ST* wx_buf,
                       unsigned* ring, float* out_outs, float* out_h,
                       hipStream_t stream)
{
  const size_t ringBytes = (size_t)2 * B_ * 1024 * 4;  // 64 KB
  hipMemsetAsync(ring, 0, ringBytes, stream);
  conv_bf16<<<dim3(2048), dim3(256), 0, stream>>>(x, xb, M_ * D_ / 8);
  conv_bf16<<<dim3(512), dim3(256), 0, stream>>>(Wa, Wab, D_ * D_ / 8);
  conv_bf16<<<dim3(512), dim3(256), 0, stream>>>(Wx, Wxb, D_ * D_ / 8);
  gemm_front<ST><<<dim3(64, 16), dim3(256), 0, stream>>>(xb, Wab, ba, Wxb, bb,
                                                         alpha_buf, wx_buf);
  void* args[] = {(void*)&h0,     (void*)&Wh,   (void*)&alpha_buf,
                  (void*)&wx_buf, (void*)&ring, (void*)&out_outs,
                  (void*)&out_h};
  hipLaunchCooperativeKernel(reinterpret_cast<void*>(&scan_rec<ST>), dim3(128),
                             dim3(256), args, 0, stream);
}

extern "C" void kernel_launch(void* const* d_in, const int* in_sizes, int n_in,
                              void* d_out, int out_size, void* d_ws,
                              size_t ws_size, hipStream_t stream)
{
  const float* x = (const float*)d_in[0];
  const float* h0 = (const float*)d_in[1];
  const float* Wa = (const float*)d_in[2];
  const float* ba = (const float*)d_in[3];
  const float* Wh = (const float*)d_in[4];
  const float* Wx = (const float*)d_in[5];
  const float* bb = (const float*)d_in[6];

  float* out_outs = (float*)d_out;
  float* out_h = out_outs + (size_t)T_ * B_ * D_;

  char* ws = (char*)d_ws;
  const size_t nMD = (size_t)M_ * D_;  // 8,388,608
  const size_t nDD = (size_t)D_ * D_;  // 1,048,576

  __hip_bfloat16* xb = (__hip_bfloat16*)ws;
  __hip_bfloat16* Wab = (__hip_bfloat16*)(ws + nMD * 2);
  __hip_bfloat16* Wxb = (__hip_bfloat16*)(ws + nMD * 2 + nDD * 2);
  char* rest = ws + nMD * 2 + 2 * nDD * 2;

  const size_t ringBytes = (size_t)2 * B_ * 1024 * 4;  // 65536
  const size_t needF32 = (size_t)(rest - ws) + 2 * nMD * 4 + ringBytes;

  if (ws_size >= needF32) {
    float* alpha_buf = (float*)rest;
    float* wx_buf = (float*)(rest + nMD * 4);
    unsigned* ring = (unsigned*)(rest + 2 * nMD * 4);
    launch_all<float>(x, h0, Wa, ba, Wh, Wx, bb, xb, Wab, Wxb, alpha_buf,
                      wx_buf, ring, out_outs, out_h, stream);
  } else {
    __hip_bfloat16* alpha_buf = (__hip_bfloat16*)rest;
    __hip_bfloat16* wx_buf = (__hip_bfloat16*)(rest + nMD * 2);
    unsigned* ring = (unsigned*)(rest + 2 * nMD * 2);
    launch_all<__hip_bfloat16>(x, h0, Wa, ba, Wh, Wx, bb, xb, Wab, Wxb,
                               alpha_buf, wx_buf, ring, out_outs, out_h,
                               stream);
  }
}

// Round 12
// 1963.322 us; speedup vs baseline: 1.0160x; 1.0160x over previous
//
#include <hip/hip_runtime.h>
#include <hip/hip_bf16.h>
#include <hip/hip_cooperative_groups.h>

typedef __attribute__((ext_vector_type(8))) short bf16x8;
typedef __attribute__((ext_vector_type(4))) float f32x4;
typedef __attribute__((ext_vector_type(4))) unsigned int u32x4;

#define D_ 1024
#define T_ 1024
#define B_ 8
#define M_ (T_ * B_)

__device__ __forceinline__ float ldv(const float* p) { return *p; }
__device__ __forceinline__ float ldv(const __hip_bfloat16* p) { return __bfloat162float(*p); }
__device__ __forceinline__ void stv(float* p, float v) { *p = v; }
__device__ __forceinline__ void stv(__hip_bfloat16* p, float v) { *p = __float2bfloat16(v); }

// --- MALL-coherent accessors (round-4/7-proven): sc0 sc1 bypasses L1+L2 ----
__device__ __forceinline__ u32x4 ld_chunk(const unsigned* p) {
  u32x4 v;
  asm volatile("global_load_dwordx4 %0, %1, off sc0 sc1" : "=v"(v) : "v"(p) : "memory");
  return v;
}
__device__ __forceinline__ void st_word(unsigned* p, unsigned v) {
  asm volatile("global_store_dword %0, %1, off sc0 sc1" :: "v"(p), "v"(v) : "memory");
}
__device__ __forceinline__ void wait_vm0() {
  asm volatile("s_waitcnt vmcnt(0)" ::: "memory");
}
// LDS-only workgroup barrier (no vmcnt drain).
__device__ __forceinline__ void bar_lds() {
  asm volatile("s_waitcnt lgkmcnt(0)\n\ts_barrier" ::: "memory");
  __builtin_amdgcn_sched_barrier(0);
}
// native 2^x / 1/x
__device__ __forceinline__ float exp2_fast(float x) {
  float r;
  asm("v_exp_f32 %0, %1" : "=v"(r) : "v"(x));
  return r;
}
__device__ __forceinline__ float rcp_fast(float x) {
  float r;
  asm("v_rcp_f32 %0, %1" : "=v"(r) : "v"(x));
  return r;
}

// ---------------------------------------------------------------------------
// f32 -> bf16 bulk convert (8 elems/thread, vectorized)
// ---------------------------------------------------------------------------
__global__ __launch_bounds__(256) void conv_bf16(const float* __restrict__ in,
                                                 __hip_bfloat16* __restrict__ out,
                                                 int n8)
{
  int i = blockIdx.x * blockDim.x + threadIdx.x;
  const int stride = gridDim.x * blockDim.x;
  for (; i < n8; i += stride) {
    const f32x4* p = reinterpret_cast<const f32x4*>(in + (size_t)i * 8);
    f32x4 a = p[0], b = p[1];
    union { bf16x8 v; __hip_bfloat16 e[8]; } u;
#pragma unroll
    for (int j = 0; j < 4; ++j) {
      u.e[j] = __float2bfloat16(a[j]);
      u.e[j + 4] = __float2bfloat16(b[j]);
    }
    *reinterpret_cast<bf16x8*>(out + (size_t)i * 8) = u.v;
  }
}

// ---------------------------------------------------------------------------
// Phase 1: alpha_all = sigmoid(xb @ Wab^T + b_alpha), wx_all = xb @ Wxb^T + b
// (unchanged — verified correct)
// ---------------------------------------------------------------------------
template <typename ST>
__global__ __launch_bounds__(256) void gemm_front(
    const __hip_bfloat16* __restrict__ xb,
    const __hip_bfloat16* __restrict__ Wab,
    const float* __restrict__ ba,
    const __hip_bfloat16* __restrict__ Wxb,
    const float* __restrict__ bbias,
    ST* __restrict__ alpha_out,
    ST* __restrict__ wx_out)
{
  const int tid = threadIdx.x;
  const int lane = tid & 63;
  const int w = tid >> 6;
  const int r = lane & 15;
  const int g = lane >> 4;
  const bool isA = blockIdx.y < 8;
  const int m0 = blockIdx.x * 128 + (w >> 1) * 64;
  const int n0 = (blockIdx.y & 7) * 128 + (w & 1) * 64;
  const __hip_bfloat16* __restrict__ W = isA ? Wab : Wxb;
  ST* __restrict__ outp = isA ? alpha_out : wx_out;

  f32x4 acc[4][4] = {};

  const __hip_bfloat16* aBase = xb + (size_t)(m0 + r) * D_ + g * 8;
  const __hip_bfloat16* bBase = W + (size_t)(n0 + r) * D_ + g * 8;

  for (int k = 0; k < D_; k += 32) {
    bf16x8 a[4], b[4];
#pragma unroll
    for (int mt = 0; mt < 4; ++mt)
      a[mt] = *reinterpret_cast<const bf16x8*>(aBase + (size_t)mt * 16 * D_ + k);
#pragma unroll
    for (int nt = 0; nt < 4; ++nt)
      b[nt] = *reinterpret_cast<const bf16x8*>(bBase + (size_t)nt * 16 * D_ + k);
#pragma unroll
    for (int mt = 0; mt < 4; ++mt)
#pragma unroll
      for (int nt = 0; nt < 4; ++nt)
        acc[mt][nt] = __builtin_amdgcn_mfma_f32_16x16x32_bf16(a[mt], b[nt], acc[mt][nt], 0, 0, 0);
  }

#pragma unroll
  for (int nt = 0; nt < 4; ++nt) {
    const int col = n0 + nt * 16 + r;
    const float bias = isA ? ba[col] : bbias[col];
#pragma unroll
    for (int mt = 0; mt < 4; ++mt) {
      const int row = m0 + mt * 16 + g * 4;
#pragma unroll
      for (int i = 0; i < 4; ++i) {
        float v = acc[mt][nt][i] + bias;
        if (isA) v = 1.0f / (1.0f + expf(-v));
        stv(outp + (size_t)(row + i) * D_ + col, v);
      }
    }
  }
}

// ---------------------------------------------------------------------------
// Phase 2: batch-island scan, word-atomic tag-in-payload, MALL scope.
// r12 = r10 structure with a SINGLE barrier per step:
//  - Wave->K-quarter remap: qw = (s>>2 + w) & 3, so WAVE 0 owns the quarter
//    containing the WG's own slice.  finish (wave 0) writes h_lds[own] and
//    wave 0's own MFMA reads it -> program order, no barrier.  Waves 1-3
//    stage all-foreign quarters -> h_lds wave-private.
//  - C_lds parity-double-buffered [2][4][64] (r10's conflict-free layout);
//    WAR edge supplied by NEXT step's bar#1 (w's write(t+2,p) comes after
//    bar#1(t+1) which comes after wave0's read(t,p)).
//  - Own slice stays in LDS (r11's ring own-slice cost an extra MALL RTT).
//  - Per-lane poll exit (satisfied lanes stop loading).
// Ring depth-2 lap-safety through the single barrier: X.finish(t) overwrite
// <- X.stage(t) observed tags t+1 from ALL 16 producers <- each producer's
// bar#1(t-1) <- its waves' complete stage(t-1) reads of parity (t+1)&1.
// ---------------------------------------------------------------------------
template <typename ST>
__global__ __launch_bounds__(256) void scan_rec(
    const float* __restrict__ h0,
    const float* __restrict__ Wh,
    const ST* __restrict__ alpha_all,
    const ST* __restrict__ wx_all,
    unsigned* __restrict__ ring,     // [2][B][1024] u32 words, memset 0
    float* __restrict__ out_outs,    // [T][B][D] f32
    float* __restrict__ out_h)       // [T+1][B][D] f32
{
  __shared__ __align__(16) unsigned short W_lds[64 * 1024];  // 128 KB, swizzled
  __shared__ __align__(16) unsigned short h_lds[1024];       // wave-private quarters
  __shared__ float C_lds[2][4][64];                          // [parity][wave][col]

  const int tid = threadIdx.x;
  const int lane = tid & 63;
  const int w = tid >> 6;
  const int r = lane & 15;
  const int g = lane >> 4;
  const int bb = blockIdx.x & 7;   // batch
  const int s = blockIdx.x >> 3;   // col slice
  const int e0 = s * 64;
  const int qw = ((s >> 2) + w) & 3;  // wave w's K-quarter (wave 0 -> own)

  // ---- Stage W_h rows e0..e0+63 into LDS as bf16, XOR-swizzled ----
  for (int idx = tid; idx < 64 * 128; idx += 256) {
    const int row = idx >> 7;        // 0..63
    const int k8 = (idx & 127) * 8;  // k chunk start
    const f32x4* p = reinterpret_cast<const f32x4*>(Wh + (size_t)(e0 + row) * D_ + k8);
    f32x4 a = p[0], bv = p[1];
    union { bf16x8 v; __hip_bfloat16 e[8]; } u;
#pragma unroll
    for (int j = 0; j < 4; ++j) {
      u.e[j] = __float2bfloat16(a[j]);
      u.e[j + 4] = __float2bfloat16(bv[j]);
    }
    const unsigned byteoff = ((unsigned)row * 2048u + (unsigned)k8 * 2u) ^ (((unsigned)row & 7u) << 4);
    *reinterpret_cast<bf16x8*>(reinterpret_cast<char*>(W_lds) + byteoff) = u.v;
  }

  // ---- Init: finish threads (wave 0, col e0+tid); publish slot0 tag=1 ----
  const int e = e0 + (tid & 63);  // finish col (valid for tid<64)
  float h_f = 0.0f, wx_c = 0.0f, al_c = 0.0f;
  if (tid < 64) {
    h_f = h0[bb * D_ + e];
    out_h[(size_t)bb * D_ + e] = h_f;
    const unsigned short hb = ((__hip_bfloat16_raw)__float2bfloat16(h_f)).x;
    h_lds[e] = hb;  // own slice lives in wave 0's quarter
    st_word(ring + (size_t)bb * 1024 + e, (unsigned)hb | (1u << 16));
    wx_c = ldv(wx_all + (size_t)bb * D_ + e);
    al_c = ldv(alpha_all + (size_t)bb * D_ + e);
  }
  __syncthreads();  // W_lds + h_lds init visible (one-time)

  for (int t = 0; t < T_; ++t) {
    // ---- stage h[t] quarter (lanes 0..31, 8 words each; skip own slice) ----
    const unsigned want = (unsigned)(t + 1);
    const int kk = qw * 256 + lane * 8;
    if (lane < 32 && (kk >> 6) != s) {
      const unsigned* cp = ring + ((size_t)(t & 1) * B_ + bb) * 1024 + kk;
      u32x4 A, Bv;
      int bail = 0;
      for (;;) {
        A = ld_chunk(cp);
        Bv = ld_chunk(cp + 4);
        wait_vm0();
        const bool ok = (A[0] >> 16) == want && (A[1] >> 16) == want &&
                        (A[2] >> 16) == want && (A[3] >> 16) == want &&
                        (Bv[0] >> 16) == want && (Bv[1] >> 16) == want &&
                        (Bv[2] >> 16) == want && (Bv[3] >> 16) == want;
        if (ok || ++bail > (1 << 20)) break;  // per-lane exit
      }
      u32x4 hw;
      hw[0] = (A[0] & 0xffffu) | (A[1] << 16);
      hw[1] = (A[2] & 0xffffu) | (A[3] << 16);
      hw[2] = (Bv[0] & 0xffffu) | (Bv[1] << 16);
      hw[3] = (Bv[2] & 0xffffu) | (Bv[3] << 16);
      *reinterpret_cast<u32x4*>(&h_lds[kk]) = hw;
    }
    asm volatile("s_waitcnt lgkmcnt(0)" ::: "memory");
    __builtin_amdgcn_sched_barrier(0);

    // ---- MFMA: y_partial[64] over this wave's K quarter ----
    f32x4 acc[4] = {};
#pragma unroll
    for (int kt = 0; kt < 8; ++kt) {
      const int k = qw * 256 + kt * 32 + g * 8;
      bf16x8 afrag = {};
      if (r == 0)
        afrag = *reinterpret_cast<const bf16x8*>(&h_lds[k]);
#pragma unroll
      for (int nt = 0; nt < 4; ++nt) {
        const unsigned row = (unsigned)(nt * 16 + r);
        const unsigned byteoff = (row * 2048u + (unsigned)k * 2u) ^ ((row & 7u) << 4);
        bf16x8 bfrag = *reinterpret_cast<const bf16x8*>(
            reinterpret_cast<const char*>(W_lds) + byteoff);
        acc[nt] = __builtin_amdgcn_mfma_f32_16x16x32_bf16(afrag, bfrag, acc[nt], 0, 0, 0);
      }
    }
    if (g == 0) {
#pragma unroll
      for (int nt = 0; nt < 4; ++nt)
        C_lds[t & 1][w][nt * 16 + r] = acc[nt][0];
    }
    bar_lds();  // C_lds handoff — the ONLY per-step barrier

    // ---- finish (wave 0): recurrence; tagged publish FIRST, outputs after ----
    if (tid < 64) {
      const float y = C_lds[t & 1][0][tid] + C_lds[t & 1][1][tid] +
                      C_lds[t & 1][2][tid] + C_lds[t & 1][3][tid];
      // tanh(x) = 1 - 2/(2^(2x*log2e)+1)
      const float xs = (y + wx_c) * 2.8853900817779268f;
      const float tv = fmaf(-2.0f, rcp_fast(exp2_fast(xs) + 1.0f), 1.0f);
      h_f = fmaf(al_c, h_f - tv, tv);  // alpha*h + (1-alpha)*v
      const unsigned short hb = ((__hip_bfloat16_raw)__float2bfloat16(h_f)).x;
      h_lds[e] = hb;  // own slice: wave-0-private (its own quarter), no barrier
      st_word(ring + ((size_t)((t + 1) & 1) * B_ + bb) * 1024 + e,
              (unsigned)hb | ((unsigned)(t + 2) << 16));
      // off-chain work after the publish:
      const float sg = rcp_fast(1.0f + exp2_fast(h_f * -1.4426950408889634f));
      const float o = h_f * h_f * sg;  // h * silu(h)
      out_h[(size_t)(t + 1) * (B_ * D_) + (size_t)bb * D_ + e] = h_f;
      out_outs[(size_t)t * (B_ * D_) + (size_t)bb * D_ + e] = o;
      if (t + 1 < T_) {
        wx_c = ldv(wx_all + (size_t)((t + 1) * B_ + bb) * D_ + e);
        al_c = ldv(alpha_all + (size_t)((t + 1) * B_ + bb) * D_ + e);
      }
    }
    // no second barrier: h_lds quarters wave-private; C_lds parity + next
    // step's bar#1 provide the WAR edge; waves 1-3 free-run into poll(t+1).
  }
}

// ---------------------------------------------------------------------------
template <typename ST>
static void launch_all(const float* x, const float* h0, const float* Wa,
                       const float* ba, const float* Wh, const float* Wx,
                       const float* bb, __hip_bfloat16* xb, __hip_bfloat16* Wab,
                       __hip_bfloat16* Wxb, ST* alpha_buf, ST* wx_buf,
                       unsigned* ring, float* out_outs, float* out_h,
                       hipStream_t stream)
{
  const size_t ringBytes = (size_t)2 * B_ * 1024 * 4;  // 64 KB
  hipMemsetAsync(ring, 0, ringBytes, stream);
  conv_bf16<<<dim3(2048), dim3(256), 0, stream>>>(x, xb, M_ * D_ / 8);
  conv_bf16<<<dim3(512), dim3(256), 0, stream>>>(Wa, Wab, D_ * D_ / 8);
  conv_bf16<<<dim3(512), dim3(256), 0, stream>>>(Wx, Wxb, D_ * D_ / 8);
  gemm_front<ST><<<dim3(64, 16), dim3(256), 0, stream>>>(xb, Wab, ba, Wxb, bb,
                                                         alpha_buf, wx_buf);
  void* args[] = {(void*)&h0,     (void*)&Wh,   (void*)&alpha_buf,
                  (void*)&wx_buf, (void*)&ring, (void*)&out_outs,
                  (void*)&out_h};
  hipLaunchCooperativeKernel(reinterpret_cast<void*>(&scan_rec<ST>), dim3(128),
                             dim3(256), args, 0, stream);
}

extern "C" void kernel_launch(void* const* d_in, const int* in_sizes, int n_in,
                              void* d_out, int out_size, void* d_ws,
                              size_t ws_size, hipStream_t stream)
{
  const float* x = (const float*)d_in[0];
  const float* h0 = (const float*)d_in[1];
  const float* Wa = (const float*)d_in[2];
  const float* ba = (const float*)d_in[3];
  const float* Wh = (const float*)d_in[4];
  const float* Wx = (const float*)d_in[5];
  const float* bb = (const float*)d_in[6];

  float* out_outs = (float*)d_out;
  float* out_h = out_outs + (size_t)T_ * B_ * D_;

  char* ws = (char*)d_ws;
  const size_t nMD = (size_t)M_ * D_;  // 8,388,608
  const size_t nDD = (size_t)D_ * D_;  // 1,048,576

  __hip_bfloat16* xb = (__hip_bfloat16*)ws;
  __hip_bfloat16* Wab = (__hip_bfloat16*)(ws + nMD * 2);
  __hip_bfloat16* Wxb = (__hip_bfloat16*)(ws + nMD * 2 + nDD * 2);
  char* rest = ws + nMD * 2 + 2 * nDD * 2;

  const size_t ringBytes = (size_t)2 * B_ * 1024 * 4;  // 65536
  const size_t needF32 = (size_t)(rest - ws) + 2 * nMD * 4 + ringBytes;

  if (ws_size >= needF32) {
    float* alpha_buf = (float*)rest;
    float* wx_buf = (float*)(rest + nMD * 4);
    unsigned* ring = (unsigned*)(rest + 2 * nMD * 4);
    launch_all<float>(x, h0, Wa, ba, Wh, Wx, bb, xb, Wab, Wxb, alpha_buf,
                      wx_buf, ring, out_outs, out_h, stream);
  } else {
    __hip_bfloat16* alpha_buf = (__hip_bfloat16*)rest;
    __hip_bfloat16* wx_buf = (__hip_bfloat16*)(rest + nMD * 2);
    unsigned* ring = (unsigned*)(rest + 2 * nMD * 2);
    launch_all<__hip_bfloat16>(x, h0, Wa, ba, Wh, Wx, bb, xb, Wab, Wxb,
                               alpha_buf, wx_buf, ring, out_outs, out_h,
                               stream);
  }
}

// Round 13
// 1758.833 us; speedup vs baseline: 1.1341x; 1.1163x over previous
//
#include <hip/hip_runtime.h>
#include <hip/hip_bf16.h>
#include <hip/hip_cooperative_groups.h>

typedef __attribute__((ext_vector_type(8))) short bf16x8;
typedef __attribute__((ext_vector_type(4))) float f32x4;
typedef __attribute__((ext_vector_type(4))) unsigned int u32x4;

#define D_ 1024
#define T_ 1024
#define B_ 8
#define M_ (T_ * B_)

__device__ __forceinline__ float ldv(const float* p) { return *p; }
__device__ __forceinline__ float ldv(const __hip_bfloat16* p) { return __bfloat162float(*p); }
__device__ __forceinline__ void stv(float* p, float v) { *p = v; }
__device__ __forceinline__ void stv(__hip_bfloat16* p, float v) { *p = __float2bfloat16(v); }

// --- MALL-coherent accessors (round-4/7-proven): sc0 sc1 bypasses L1+L2 ----
__device__ __forceinline__ u32x4 ld_chunk(const unsigned* p) {
  u32x4 v;
  asm volatile("global_load_dwordx4 %0, %1, off sc0 sc1" : "=v"(v) : "v"(p) : "memory");
  return v;
}
__device__ __forceinline__ void st_word(unsigned* p, unsigned v) {
  asm volatile("global_store_dword %0, %1, off sc0 sc1" :: "v"(p), "v"(v) : "memory");
}
__device__ __forceinline__ void wait_vm0() {
  asm volatile("s_waitcnt vmcnt(0)" ::: "memory");
}
// LDS-only workgroup barrier (no vmcnt drain).
__device__ __forceinline__ void bar_lds() {
  asm volatile("s_waitcnt lgkmcnt(0)\n\ts_barrier" ::: "memory");
  __builtin_amdgcn_sched_barrier(0);
}
// native 2^x / 1/x
__device__ __forceinline__ float exp2_fast(float x) {
  float r;
  asm("v_exp_f32 %0, %1" : "=v"(r) : "v"(x));
  return r;
}
__device__ __forceinline__ float rcp_fast(float x) {
  float r;
  asm("v_rcp_f32 %0, %1" : "=v"(r) : "v"(x));
  return r;
}

// ---------------------------------------------------------------------------
// f32 -> bf16 bulk convert (8 elems/thread, vectorized)
// ---------------------------------------------------------------------------
__global__ __launch_bounds__(256) void conv_bf16(const float* __restrict__ in,
                                                 __hip_bfloat16* __restrict__ out,
                                                 int n8)
{
  int i = blockIdx.x * blockDim.x + threadIdx.x;
  const int stride = gridDim.x * blockDim.x;
  for (; i < n8; i += stride) {
    const f32x4* p = reinterpret_cast<const f32x4*>(in + (size_t)i * 8);
    f32x4 a = p[0], b = p[1];
    union { bf16x8 v; __hip_bfloat16 e[8]; } u;
#pragma unroll
    for (int j = 0; j < 4; ++j) {
      u.e[j] = __float2bfloat16(a[j]);
      u.e[j + 4] = __float2bfloat16(b[j]);
    }
    *reinterpret_cast<bf16x8*>(out + (size_t)i * 8) = u.v;
  }
}

// ---------------------------------------------------------------------------
// Phase 1: alpha_all = sigmoid(xb @ Wab^T + b_alpha), wx_all = xb @ Wxb^T + b
// (unchanged — verified correct)
// ---------------------------------------------------------------------------
template <typename ST>
__global__ __launch_bounds__(256) void gemm_front(
    const __hip_bfloat16* __restrict__ xb,
    const __hip_bfloat16* __restrict__ Wab,
    const float* __restrict__ ba,
    const __hip_bfloat16* __restrict__ Wxb,
    const float* __restrict__ bbias,
    ST* __restrict__ alpha_out,
    ST* __restrict__ wx_out)
{
  const int tid = threadIdx.x;
  const int lane = tid & 63;
  const int w = tid >> 6;
  const int r = lane & 15;
  const int g = lane >> 4;
  const bool isA = blockIdx.y < 8;
  const int m0 = blockIdx.x * 128 + (w >> 1) * 64;
  const int n0 = (blockIdx.y & 7) * 128 + (w & 1) * 64;
  const __hip_bfloat16* __restrict__ W = isA ? Wab : Wxb;
  ST* __restrict__ outp = isA ? alpha_out : wx_out;

  f32x4 acc[4][4] = {};

  const __hip_bfloat16* aBase = xb + (size_t)(m0 + r) * D_ + g * 8;
  const __hip_bfloat16* bBase = W + (size_t)(n0 + r) * D_ + g * 8;

  for (int k = 0; k < D_; k += 32) {
    bf16x8 a[4], b[4];
#pragma unroll
    for (int mt = 0; mt < 4; ++mt)
      a[mt] = *reinterpret_cast<const bf16x8*>(aBase + (size_t)mt * 16 * D_ + k);
#pragma unroll
    for (int nt = 0; nt < 4; ++nt)
      b[nt] = *reinterpret_cast<const bf16x8*>(bBase + (size_t)nt * 16 * D_ + k);
#pragma unroll
    for (int mt = 0; mt < 4; ++mt)
#pragma unroll
      for (int nt = 0; nt < 4; ++nt)
        acc[mt][nt] = __builtin_amdgcn_mfma_f32_16x16x32_bf16(a[mt], b[nt], acc[mt][nt], 0, 0, 0);
  }

#pragma unroll
  for (int nt = 0; nt < 4; ++nt) {
    const int col = n0 + nt * 16 + r;
    const float bias = isA ? ba[col] : bbias[col];
#pragma unroll
    for (int mt = 0; mt < 4; ++mt) {
      const int row = m0 + mt * 16 + g * 4;
#pragma unroll
      for (int i = 0; i < 4; ++i) {
        float v = acc[mt][nt][i] + bias;
        if (isA) v = 1.0f / (1.0f + expf(-v));
        stv(outp + (size_t)(row + i) * D_ + col, v);
      }
    }
  }
}

// ---------------------------------------------------------------------------
// Phase 2: batch-island scan, word-atomic tag-in-payload, MALL scope only.
// Structure = round 10 EXACTLY (best measured: 1603 us scan, 1.57 us/step).
// Two bar_lds per step; wave-local stage->MFMA overlap; own slice through
// LDS; fast tanh.  r11/r12 showed the second barrier's phase-alignment is
// load-bearing: free-running polls sample on an RTT-quantized period and
// discover LATER on average; the lockstep schedule's first poll usually hits.
// ---------------------------------------------------------------------------
template <typename ST>
__global__ __launch_bounds__(256) void scan_rec(
    const float* __restrict__ h0,
    const float* __restrict__ Wh,
    const ST* __restrict__ alpha_all,
    const ST* __restrict__ wx_all,
    unsigned* __restrict__ ring,     // [2][B][1024] u32 words, memset 0
    float* __restrict__ out_outs,    // [T][B][D] f32
    float* __restrict__ out_h)       // [T+1][B][D] f32
{
  __shared__ __align__(16) unsigned short W_lds[64 * 1024];  // 128 KB, swizzled
  __shared__ __align__(16) unsigned short h_lds[1024];       // h[t] bf16
  __shared__ float C_lds[4][64];                             // per-wave partials

  const int tid = threadIdx.x;
  const int lane = tid & 63;
  const int w = tid >> 6;
  const int r = lane & 15;
  const int g = lane >> 4;
  const int bb = blockIdx.x & 7;   // batch
  const int s = blockIdx.x >> 3;   // col slice
  const int e0 = s * 64;

  // ---- Stage W_h rows e0..e0+63 into LDS as bf16, XOR-swizzled ----
  for (int idx = tid; idx < 64 * 128; idx += 256) {
    const int row = idx >> 7;        // 0..63
    const int k8 = (idx & 127) * 8;  // k chunk start
    const f32x4* p = reinterpret_cast<const f32x4*>(Wh + (size_t)(e0 + row) * D_ + k8);
    f32x4 a = p[0], bv = p[1];
    union { bf16x8 v; __hip_bfloat16 e[8]; } u;
#pragma unroll
    for (int j = 0; j < 4; ++j) {
      u.e[j] = __float2bfloat16(a[j]);
      u.e[j + 4] = __float2bfloat16(bv[j]);
    }
    const unsigned byteoff = ((unsigned)row * 2048u + (unsigned)k8 * 2u) ^ (((unsigned)row & 7u) << 4);
    *reinterpret_cast<bf16x8*>(reinterpret_cast<char*>(W_lds) + byteoff) = u.v;
  }

  // ---- Init: finish threads (wave 0, col e0+tid); publish slot0 tag=1 ----
  float h_f = 0.0f, wx_c = 0.0f, al_c = 0.0f;
  if (tid < 64) {
    const int e = e0 + tid;
    h_f = h0[bb * D_ + e];
    out_h[(size_t)bb * D_ + e] = h_f;
    const unsigned short hb = ((__hip_bfloat16_raw)__float2bfloat16(h_f)).x;
    h_lds[e] = hb;
    st_word(ring + (size_t)bb * 1024 + e, (unsigned)hb | (1u << 16));
    wx_c = ldv(wx_all + (size_t)bb * D_ + e);
    al_c = ldv(alpha_all + (size_t)bb * D_ + e);
  }
  __syncthreads();  // W_lds + h_lds init visible

  for (int t = 0; t < T_; ++t) {
    // ---- stage h[t] quarter: spin on tagged words (lanes 0..31, not own) ----
    const unsigned want = (unsigned)(t + 1);
    const int kk = w * 256 + lane * 8;
    if (lane < 32 && (kk >> 6) != s) {
      const unsigned* cp = ring + ((size_t)(t & 1) * B_ + bb) * 1024 + kk;
      u32x4 A, Bv;
      int bail = 0;
      for (;;) {
        A = ld_chunk(cp);
        Bv = ld_chunk(cp + 4);
        wait_vm0();
        const bool ok = (A[0] >> 16) == want && (A[1] >> 16) == want &&
                        (A[2] >> 16) == want && (A[3] >> 16) == want &&
                        (Bv[0] >> 16) == want && (Bv[1] >> 16) == want &&
                        (Bv[2] >> 16) == want && (Bv[3] >> 16) == want;
        if (__all(ok)) break;
        if (++bail > (1 << 20)) break;  // hang insurance only
      }
      u32x4 hw;
      hw[0] = (A[0] & 0xffffu) | (A[1] << 16);
      hw[1] = (A[2] & 0xffffu) | (A[3] << 16);
      hw[2] = (Bv[0] & 0xffffu) | (Bv[1] << 16);
      hw[3] = (Bv[2] & 0xffffu) | (Bv[3] << 16);
      *reinterpret_cast<u32x4*>(&h_lds[kk]) = hw;
    }
    asm volatile("s_waitcnt lgkmcnt(0)" ::: "memory");
    __builtin_amdgcn_sched_barrier(0);

    // ---- MFMA: y_partial[64] over this wave's K quarter ----
    f32x4 acc[4] = {};
#pragma unroll
    for (int kt = 0; kt < 8; ++kt) {
      const int k = w * 256 + kt * 32 + g * 8;
      bf16x8 afrag = {};
      if (r == 0)
        afrag = *reinterpret_cast<const bf16x8*>(&h_lds[k]);
#pragma unroll
      for (int nt = 0; nt < 4; ++nt) {
        const unsigned row = (unsigned)(nt * 16 + r);
        const unsigned byteoff = (row * 2048u + (unsigned)k * 2u) ^ ((row & 7u) << 4);
        bf16x8 bfrag = *reinterpret_cast<const bf16x8*>(
            reinterpret_cast<const char*>(W_lds) + byteoff);
        acc[nt] = __builtin_amdgcn_mfma_f32_16x16x32_bf16(afrag, bfrag, acc[nt], 0, 0, 0);
      }
    }
    if (g == 0) {
#pragma unroll
      for (int nt = 0; nt < 4; ++nt)
        C_lds[w][nt * 16 + r] = acc[nt][0];
    }
    bar_lds();  // C_lds handoff (LDS-only hazard; no vmcnt drain)

    // ---- finish (wave 0): recurrence; tagged publish FIRST, outputs after ----
    if (tid < 64) {
      const int e = e0 + tid;
      const float y = C_lds[0][tid] + C_lds[1][tid] + C_lds[2][tid] + C_lds[3][tid];
      // tanh(x) = 1 - 2/(2^(2x*log2e)+1)  [native exp2+rcp, ~16cy]
      const float xs = (y + wx_c) * 2.8853900817779268f;
      const float tv = fmaf(-2.0f, rcp_fast(exp2_fast(xs) + 1.0f), 1.0f);
      h_f = fmaf(al_c, h_f - tv, tv);  // alpha*h + (1-alpha)*v
      const unsigned short hb = ((__hip_bfloat16_raw)__float2bfloat16(h_f)).x;
      h_lds[e] = hb;  // own slice short-circuit for next step
      st_word(ring + ((size_t)((t + 1) & 1) * B_ + bb) * 1024 + e,
              (unsigned)hb | ((unsigned)(t + 2) << 16));
      // off-chain work after the publish:
      const float sg = rcp_fast(1.0f + exp2_fast(h_f * -1.4426950408889634f));
      const float o = h_f * h_f * sg;  // h * silu(h)
      out_h[(size_t)(t + 1) * (B_ * D_) + (size_t)bb * D_ + e] = h_f;
      out_outs[(size_t)t * (B_ * D_) + (size_t)bb * D_ + e] = o;
      if (t + 1 < T_) {
        wx_c = ldv(wx_all + (size_t)((t + 1) * B_ + bb) * D_ + e);
        al_c = ldv(alpha_all + (size_t)((t + 1) * B_ + bb) * D_ + e);
      }
    }
    bar_lds();  // h_lds(own slice) visible; C_lds reusable (LDS-only hazard)
  }
}

// ---------------------------------------------------------------------------
template <typename ST>
static void launch_all(const float* x, const float* h0, const float* Wa,
                       const float* ba, const float* Wh, const float* Wx,
                       const float* bb, __hip_bfloat16* xb, __hip_bfloat16* Wab,
                       __hip_bfloat16* Wxb, ST* alpha_buf, ST* wx_buf,
                       unsigned* ring, float* out_outs, float* out_h,
                       hipStream_t stream)
{
  const size_t ringBytes = (size_t)2 * B_ * 1024 * 4;  // 64 KB
  hipMemsetAsync(ring, 0, ringBytes, stream);
  conv_bf16<<<dim3(2048), dim3(256), 0, stream>>>(x, xb, M_ * D_ / 8);
  conv_bf16<<<dim3(512), dim3(256), 0, stream>>>(Wa, Wab, D_ * D_ / 8);
  conv_bf16<<<dim3(512), dim3(256), 0, stream>>>(Wx, Wxb, D_ * D_ / 8);
  gemm_front<ST><<<dim3(64, 16), dim3(256), 0, stream>>>(xb, Wab, ba, Wxb, bb,
                                                         alpha_buf, wx_buf);
  void* args[] = {(void*)&h0,     (void*)&Wh,   (void*)&alpha_buf,
                  (void*)&wx_buf, (void*)&ring, (void*)&out_outs,
                  (void*)&out_h};
  hipLaunchCooperativeKernel(reinterpret_cast<void*>(&scan_rec<ST>), dim3(128),
                             dim3(256), args, 0, stream);
}

extern "C" void kernel_launch(void* const* d_in, const int* in_sizes, int n_in,
                              void* d_out, int out_size, void* d_ws,
                              size_t ws_size, hipStream_t stream)
{
  const float* x = (const float*)d_in[0];
  const float* h0 = (const float*)d_in[1];
  const float* Wa = (const float*)d_in[2];
  const float* ba = (const float*)d_in[3];
  const float* Wh = (const float*)d_in[4];
  const float* Wx = (const float*)d_in[5];
  const float* bb = (const float*)d_in[6];

  float* out_outs = (float*)d_out;
  float* out_h = out_outs + (size_t)T_ * B_ * D_;

  char* ws = (char*)d_ws;
  const size_t nMD = (size_t)M_ * D_;  // 8,388,608
  const size_t nDD = (size_t)D_ * D_;  // 1,048,576

  __hip_bfloat16* xb = (__hip_bfloat16*)ws;
  __hip_bfloat16* Wab = (__hip_bfloat16*)(ws + nMD * 2);
  __hip_bfloat16* Wxb = (__hip_bfloat16*)(ws + nMD * 2 + nDD * 2);
  char* rest = ws + nMD * 2 + 2 * nDD * 2;

  const size_t ringBytes = (size_t)2 * B_ * 1024 * 4;  // 65536
  const size_t needF32 = (size_t)(rest - ws) + 2 * nMD * 4 + ringBytes;

  if (ws_size >= needF32) {
    float* alpha_buf = (float*)rest;
    float* wx_buf = (float*)(rest + nMD * 4);
    unsigned* ring = (unsigned*)(rest + 2 * nMD * 4);
    launch_all<float>(x, h0, Wa, ba, Wh, Wx, bb, xb, Wab, Wxb, alpha_buf,
                      wx_buf, ring, out_outs, out_h, stream);
  } else {
    __hip_bfloat16* alpha_buf = (__hip_bfloat16*)rest;
    __hip_bfloat16* wx_buf = (__hip_bfloat16*)(rest + nMD * 2);
    unsigned* ring = (unsigned*)(rest + 2 * nMD * 2);
    launch_all<__hip_bfloat16>(x, h0, Wa, ba, Wh, Wx, bb, xb, Wab, Wxb,
                               alpha_buf, wx_buf, ring, out_outs, out_h,
                               stream);
  }
}

// Round 14
// 1690.481 us; speedup vs baseline: 1.1799x; 1.0404x over previous
//
#include <hip/hip_runtime.h>
#include <hip/hip_bf16.h>
#include <hip/hip_cooperative_groups.h>

typedef __attribute__((ext_vector_type(8))) short bf16x8;
typedef __attribute__((ext_vector_type(4))) float f32x4;
typedef __attribute__((ext_vector_type(4))) unsigned int u32x4;

#define D_ 1024
#define T_ 1024
#define B_ 8
#define M_ (T_ * B_)

__device__ __forceinline__ float ldv(const float* p) { return *p; }
__device__ __forceinline__ float ldv(const __hip_bfloat16* p) { return __bfloat162float(*p); }
__device__ __forceinline__ void stv(float* p, float v) { *p = v; }
__device__ __forceinline__ void stv(__hip_bfloat16* p, float v) { *p = __float2bfloat16(v); }

// --- MALL-coherent accessors (round-4/7-proven): sc0 sc1 bypasses L1+L2 ----
__device__ __forceinline__ u32x4 ld_chunk(const unsigned* p) {
  u32x4 v;
  asm volatile("global_load_dwordx4 %0, %1, off sc0 sc1" : "=v"(v) : "v"(p) : "memory");
  return v;
}
__device__ __forceinline__ void st_word(unsigned* p, unsigned v) {
  asm volatile("global_store_dword %0, %1, off sc0 sc1" :: "v"(p), "v"(v) : "memory");
}
__device__ __forceinline__ void wait_vm0() {
  asm volatile("s_waitcnt vmcnt(0)" ::: "memory");
}
// LDS-only workgroup barrier (no vmcnt drain).
__device__ __forceinline__ void bar_lds() {
  asm volatile("s_waitcnt lgkmcnt(0)\n\ts_barrier" ::: "memory");
  __builtin_amdgcn_sched_barrier(0);
}
// native 2^x / 1/x
__device__ __forceinline__ float exp2_fast(float x) {
  float r;
  asm("v_exp_f32 %0, %1" : "=v"(r) : "v"(x));
  return r;
}
__device__ __forceinline__ float rcp_fast(float x) {
  float r;
  asm("v_rcp_f32 %0, %1" : "=v"(r) : "v"(x));
  return r;
}

// ---------------------------------------------------------------------------
// f32 -> bf16 bulk convert (8 elems/thread, vectorized)
// ---------------------------------------------------------------------------
__global__ __launch_bounds__(256) void conv_bf16(const float* __restrict__ in,
                                                 __hip_bfloat16* __restrict__ out,
                                                 int n8)
{
  int i = blockIdx.x * blockDim.x + threadIdx.x;
  const int stride = gridDim.x * blockDim.x;
  for (; i < n8; i += stride) {
    const f32x4* p = reinterpret_cast<const f32x4*>(in + (size_t)i * 8);
    f32x4 a = p[0], b = p[1];
    union { bf16x8 v; __hip_bfloat16 e[8]; } u;
#pragma unroll
    for (int j = 0; j < 4; ++j) {
      u.e[j] = __float2bfloat16(a[j]);
      u.e[j + 4] = __float2bfloat16(b[j]);
    }
    *reinterpret_cast<bf16x8*>(out + (size_t)i * 8) = u.v;
  }
}

// ---------------------------------------------------------------------------
// Phase 1 (r14 rewrite): 128x128 tile, BK=64, double-buffered LDS, reg-staged
// 2-phase loop (T3 minimal).  Old reg-direct version was ~255 TF (no reuse,
// 64B segments); LDS halves A/B traffic and amortizes addressing.
// alpha_all = sigmoid(xb @ Wab^T + b_alpha), wx_all = xb @ Wxb^T + b.
// blockIdx.y<8 -> alpha GEMM, else wx GEMM.  4 waves (2x2), wave tile 64x64.
// ---------------------------------------------------------------------------
template <typename ST>
__global__ __launch_bounds__(256) void gemm_front(
    const __hip_bfloat16* __restrict__ xb,
    const __hip_bfloat16* __restrict__ Wab,
    const float* __restrict__ ba,
    const __hip_bfloat16* __restrict__ Wxb,
    const float* __restrict__ bbias,
    ST* __restrict__ alpha_out,
    ST* __restrict__ wx_out)
{
  __shared__ __align__(16) unsigned short As[2][128 * 64];  // 16 KB x2
  __shared__ __align__(16) unsigned short Bs[2][128 * 64];  // 16 KB x2

  const int tid = threadIdx.x;
  const int lane = tid & 63;
  const int w = tid >> 6;
  const int r = lane & 15;
  const int g = lane >> 4;
  const bool isA = blockIdx.y < 8;
  const int m0 = blockIdx.x * 128;
  const int n0 = (blockIdx.y & 7) * 128;
  const __hip_bfloat16* __restrict__ W = isA ? Wab : Wxb;
  ST* __restrict__ outp = isA ? alpha_out : wx_out;

  // staging: thread -> row sr, cols sc..sc+31 (4 x b128, 64B contiguous)
  const int sr = tid >> 1;
  const int sc = (tid & 1) * 32;
  const __hip_bfloat16* aSrc = xb + (size_t)(m0 + sr) * D_ + sc;
  const __hip_bfloat16* bSrc = W + (size_t)(n0 + sr) * D_ + sc;

  // prologue: stage k-tile 0 into buffer 0
  {
#pragma unroll
    for (int j = 0; j < 4; ++j) {
      bf16x8 av = *reinterpret_cast<const bf16x8*>(aSrc + j * 8);
      bf16x8 bv = *reinterpret_cast<const bf16x8*>(bSrc + j * 8);
      *reinterpret_cast<bf16x8*>(&As[0][sr * 64 + sc + j * 8]) = av;
      *reinterpret_cast<bf16x8*>(&Bs[0][sr * 64 + sc + j * 8]) = bv;
    }
  }
  __syncthreads();

  f32x4 acc[4][4] = {};
  const int wrow = (w >> 1) * 64;
  const int wcol = (w & 1) * 64;

  for (int kt = 0; kt < 16; ++kt) {
    const int cur = kt & 1;
    const bool more = (kt + 1 < 16);
    bf16x8 anx[4], bnx[4];
    if (more) {
      const int kn = (kt + 1) * 64;
#pragma unroll
      for (int j = 0; j < 4; ++j) {
        anx[j] = *reinterpret_cast<const bf16x8*>(aSrc + kn + j * 8);
        bnx[j] = *reinterpret_cast<const bf16x8*>(bSrc + kn + j * 8);
      }
    }
#pragma unroll
    for (int ks = 0; ks < 2; ++ks) {
      bf16x8 af[4], bf[4];
#pragma unroll
      for (int mt = 0; mt < 4; ++mt)
        af[mt] = *reinterpret_cast<const bf16x8*>(
            &As[cur][(wrow + mt * 16 + r) * 64 + ks * 32 + g * 8]);
#pragma unroll
      for (int nt = 0; nt < 4; ++nt)
        bf[nt] = *reinterpret_cast<const bf16x8*>(
            &Bs[cur][(wcol + nt * 16 + r) * 64 + ks * 32 + g * 8]);
#pragma unroll
      for (int mt = 0; mt < 4; ++mt)
#pragma unroll
        for (int nt = 0; nt < 4; ++nt)
          acc[mt][nt] = __builtin_amdgcn_mfma_f32_16x16x32_bf16(
              af[mt], bf[nt], acc[mt][nt], 0, 0, 0);
    }
    if (more) {
#pragma unroll
      for (int j = 0; j < 4; ++j) {
        *reinterpret_cast<bf16x8*>(&As[cur ^ 1][sr * 64 + sc + j * 8]) = anx[j];
        *reinterpret_cast<bf16x8*>(&Bs[cur ^ 1][sr * 64 + sc + j * 8]) = bnx[j];
      }
    }
    __syncthreads();
  }

#pragma unroll
  for (int nt = 0; nt < 4; ++nt) {
    const int col = n0 + wcol + nt * 16 + r;
    const float bias = isA ? ba[col] : bbias[col];
#pragma unroll
    for (int mt = 0; mt < 4; ++mt) {
      const int row = m0 + wrow + mt * 16 + g * 4;
#pragma unroll
      for (int i = 0; i < 4; ++i) {
        float v = acc[mt][nt][i] + bias;
        if (isA) v = 1.0f / (1.0f + expf(-v));
        stv(outp + (size_t)(row + i) * D_ + col, v);
      }
    }
  }
}

// ---------------------------------------------------------------------------
// Phase 2: batch-island scan, word-atomic tag-in-payload, MALL scope only.
// Structure = round 10/13 EXACTLY (best measured: 1603 us scan, 1.57 us/step;
// reproduced twice).  Two bar_lds per step; wave-local stage->MFMA overlap;
// own slice through LDS; fast tanh.  UNCHANGED in r14.
// ---------------------------------------------------------------------------
template <typename ST>
__global__ __launch_bounds__(256) void scan_rec(
    const float* __restrict__ h0,
    const float* __restrict__ Wh,
    const ST* __restrict__ alpha_all,
    const ST* __restrict__ wx_all,
    unsigned* __restrict__ ring,     // [2][B][1024] u32 words, memset 0
    float* __restrict__ out_outs,    // [T][B][D] f32
    float* __restrict__ out_h)       // [T+1][B][D] f32
{
  __shared__ __align__(16) unsigned short W_lds[64 * 1024];  // 128 KB, swizzled
  __shared__ __align__(16) unsigned short h_lds[1024];       // h[t] bf16
  __shared__ float C_lds[4][64];                             // per-wave partials

  const int tid = threadIdx.x;
  const int lane = tid & 63;
  const int w = tid >> 6;
  const int r = lane & 15;
  const int g = lane >> 4;
  const int bb = blockIdx.x & 7;   // batch
  const int s = blockIdx.x >> 3;   // col slice
  const int e0 = s * 64;

  // ---- Stage W_h rows e0..e0+63 into LDS as bf16, XOR-swizzled ----
  for (int idx = tid; idx < 64 * 128; idx += 256) {
    const int row = idx >> 7;        // 0..63
    const int k8 = (idx & 127) * 8;  // k chunk start
    const f32x4* p = reinterpret_cast<const f32x4*>(Wh + (size_t)(e0 + row) * D_ + k8);
    f32x4 a = p[0], bv = p[1];
    union { bf16x8 v; __hip_bfloat16 e[8]; } u;
#pragma unroll
    for (int j = 0; j < 4; ++j) {
      u.e[j] = __float2bfloat16(a[j]);
      u.e[j + 4] = __float2bfloat16(bv[j]);
    }
    const unsigned byteoff = ((unsigned)row * 2048u + (unsigned)k8 * 2u) ^ (((unsigned)row & 7u) << 4);
    *reinterpret_cast<bf16x8*>(reinterpret_cast<char*>(W_lds) + byteoff) = u.v;
  }

  // ---- Init: finish threads (wave 0, col e0+tid); publish slot0 tag=1 ----
  float h_f = 0.0f, wx_c = 0.0f, al_c = 0.0f;
  if (tid < 64) {
    const int e = e0 + tid;
    h_f = h0[bb * D_ + e];
    out_h[(size_t)bb * D_ + e] = h_f;
    const unsigned short hb = ((__hip_bfloat16_raw)__float2bfloat16(h_f)).x;
    h_lds[e] = hb;
    st_word(ring + (size_t)bb * 1024 + e, (unsigned)hb | (1u << 16));
    wx_c = ldv(wx_all + (size_t)bb * D_ + e);
    al_c = ldv(alpha_all + (size_t)bb * D_ + e);
  }
  __syncthreads();  // W_lds + h_lds init visible

  for (int t = 0; t < T_; ++t) {
    // ---- stage h[t] quarter: spin on tagged words (lanes 0..31, not own) ----
    const unsigned want = (unsigned)(t + 1);
    const int kk = w * 256 + lane * 8;
    if (lane < 32 && (kk >> 6) != s) {
      const unsigned* cp = ring + ((size_t)(t & 1) * B_ + bb) * 1024 + kk;
      u32x4 A, Bv;
      int bail = 0;
      for (;;) {
        A = ld_chunk(cp);
        Bv = ld_chunk(cp + 4);
        wait_vm0();
        const bool ok = (A[0] >> 16) == want && (A[1] >> 16) == want &&
                        (A[2] >> 16) == want && (A[3] >> 16) == want &&
                        (Bv[0] >> 16) == want && (Bv[1] >> 16) == want &&
                        (Bv[2] >> 16) == want && (Bv[3] >> 16) == want;
        if (__all(ok)) break;
        if (++bail > (1 << 20)) break;  // hang insurance only
      }
      u32x4 hw;
      hw[0] = (A[0] & 0xffffu) | (A[1] << 16);
      hw[1] = (A[2] & 0xffffu) | (A[3] << 16);
      hw[2] = (Bv[0] & 0xffffu) | (Bv[1] << 16);
      hw[3] = (Bv[2] & 0xffffu) | (Bv[3] << 16);
      *reinterpret_cast<u32x4*>(&h_lds[kk]) = hw;
    }
    asm volatile("s_waitcnt lgkmcnt(0)" ::: "memory");
    __builtin_amdgcn_sched_barrier(0);

    // ---- MFMA: y_partial[64] over this wave's K quarter ----
    f32x4 acc[4] = {};
#pragma unroll
    for (int kt = 0; kt < 8; ++kt) {
      const int k = w * 256 + kt * 32 + g * 8;
      bf16x8 afrag = {};
      if (r == 0)
        afrag = *reinterpret_cast<const bf16x8*>(&h_lds[k]);
#pragma unroll
      for (int nt = 0; nt < 4; ++nt) {
        const unsigned row = (unsigned)(nt * 16 + r);
        const unsigned byteoff = (row * 2048u + (unsigned)k * 2u) ^ ((row & 7u) << 4);
        bf16x8 bfrag = *reinterpret_cast<const bf16x8*>(
            reinterpret_cast<const char*>(W_lds) + byteoff);
        acc[nt] = __builtin_amdgcn_mfma_f32_16x16x32_bf16(afrag, bfrag, acc[nt], 0, 0, 0);
      }
    }
    if (g == 0) {
#pragma unroll
      for (int nt = 0; nt < 4; ++nt)
        C_lds[w][nt * 16 + r] = acc[nt][0];
    }
    bar_lds();  // C_lds handoff (LDS-only hazard; no vmcnt drain)

    // ---- finish (wave 0): recurrence; tagged publish FIRST, outputs after ----
    if (tid < 64) {
      const int e = e0 + tid;
      const float y = C_lds[0][tid] + C_lds[1][tid] + C_lds[2][tid] + C_lds[3][tid];
      // tanh(x) = 1 - 2/(2^(2x*log2e)+1)  [native exp2+rcp, ~16cy]
      const float xs = (y + wx_c) * 2.8853900817779268f;
      const float tv = fmaf(-2.0f, rcp_fast(exp2_fast(xs) + 1.0f), 1.0f);
      h_f = fmaf(al_c, h_f - tv, tv);  // alpha*h + (1-alpha)*v
      const unsigned short hb = ((__hip_bfloat16_raw)__float2bfloat16(h_f)).x;
      h_lds[e] = hb;  // own slice short-circuit for next step
      st_word(ring + ((size_t)((t + 1) & 1) * B_ + bb) * 1024 + e,
              (unsigned)hb | ((unsigned)(t + 2) << 16));
      // off-chain work after the publish:
      const float sg = rcp_fast(1.0f + exp2_fast(h_f * -1.4426950408889634f));
      const float o = h_f * h_f * sg;  // h * silu(h)
      out_h[(size_t)(t + 1) * (B_ * D_) + (size_t)bb * D_ + e] = h_f;
      out_outs[(size_t)t * (B_ * D_) + (size_t)bb * D_ + e] = o;
      if (t + 1 < T_) {
        wx_c = ldv(wx_all + (size_t)((t + 1) * B_ + bb) * D_ + e);
        al_c = ldv(alpha_all + (size_t)((t + 1) * B_ + bb) * D_ + e);
      }
    }
    bar_lds();  // h_lds(own slice) visible; C_lds reusable (LDS-only hazard)
  }
}

// ---------------------------------------------------------------------------
template <typename ST>
static void launch_all(const float* x, const float* h0, const float* Wa,
                       const float* ba, const float* Wh, const float* Wx,
                       const float* bb, __hip_bfloat16* xb, __hip_bfloat16* Wab,
                       __hip_bfloat16* Wxb, ST* alpha_buf, ST* wx_buf,
                       unsigned* ring, float* out_outs, float* out_h,
                       hipStream_t stream)
{
  const size_t ringBytes = (size_t)2 * B_ * 1024 * 4;  // 64 KB
  hipMemsetAsync(ring, 0, ringBytes, stream);
  conv_bf16<<<dim3(2048), dim3(256), 0, stream>>>(x, xb, M_ * D_ / 8);
  conv_bf16<<<dim3(512), dim3(256), 0, stream>>>(Wa, Wab, D_ * D_ / 8);
  conv_bf16<<<dim3(512), dim3(256), 0, stream>>>(Wx, Wxb, D_ * D_ / 8);
  gemm_front<ST><<<dim3(64, 16), dim3(256), 0, stream>>>(xb, Wab, ba, Wxb, bb,
                                                         alpha_buf, wx_buf);
  void* args[] = {(void*)&h0,     (void*)&Wh,   (void*)&alpha_buf,
                  (void*)&wx_buf, (void*)&ring, (void*)&out_outs,
                  (void*)&out_h};
  hipLaunchCooperativeKernel(reinterpret_cast<void*>(&scan_rec<ST>), dim3(128),
                             dim3(256), args, 0, stream);
}

extern "C" void kernel_launch(void* const* d_in, const int* in_sizes, int n_in,
                              void* d_out, int out_size, void* d_ws,
                              size_t ws_size, hipStream_t stream)
{
  const float* x = (const float*)d_in[0];
  const float* h0 = (const float*)d_in[1];
  const float* Wa = (const float*)d_in[2];
  const float* ba = (const float*)d_in[3];
  const float* Wh = (const float*)d_in[4];
  const float* Wx = (const float*)d_in[5];
  const float* bb = (const float*)d_in[6];

  float* out_outs = (float*)d_out;
  float* out_h = out_outs + (size_t)T_ * B_ * D_;

  char* ws = (char*)d_ws;
  const size_t nMD = (size_t)M_ * D_;  // 8,388,608
  const size_t nDD = (size_t)D_ * D_;  // 1,048,576

  __hip_bfloat16* xb = (__hip_bfloat16*)ws;
  __hip_bfloat16* Wab = (__hip_bfloat16*)(ws + nMD * 2);
  __hip_bfloat16* Wxb = (__hip_bfloat16*)(ws + nMD * 2 + nDD * 2);
  char* rest = ws + nMD * 2 + 2 * nDD * 2;

  const size_t ringBytes = (size_t)2 * B_ * 1024 * 4;  // 65536
  const size_t needF32 = (size_t)(rest - ws) + 2 * nMD * 4 + ringBytes;

  if (ws_size >= needF32) {
    float* alpha_buf = (float*)rest;
    float* wx_buf = (float*)(rest + nMD * 4);
    unsigned* ring = (unsigned*)(rest + 2 * nMD * 4);
    launch_all<float>(x, h0, Wa, ba, Wh, Wx, bb, xb, Wab, Wxb, alpha_buf,
                      wx_buf, ring, out_outs, out_h, stream);
  } else {
    __hip_bfloat16* alpha_buf = (__hip_bfloat16*)rest;
    __hip_bfloat16* wx_buf = (__hip_bfloat16*)(rest + nMD * 2);
    unsigned* ring = (unsigned*)(rest + 2 * nMD * 2);
    launch_all<__hip_bfloat16>(x, h0, Wa, ba, Wh, Wx, bb, xb, Wab, Wxb,
                               alpha_buf, wx_buf, ring, out_outs, out_h,
                               stream);
  }
}